// Round 4
// baseline (68318.298 us; speedup 1.0000x reference)
//
#include <hip/hip_runtime.h>
#include <cmath>

#define SEQ 4096
#define INP 457
#define EMB 2048
#define NWG_E 256   // encoder: 1 WG (1024 thr) per CU; 64+16 weight floats/thread -> ~116 VGPR, no spill possible
#define NWG_D 16    // decoder: 16 WGs x 32 c-indices = 512 >= 457

typedef unsigned long long u64t;

__device__ __forceinline__ float sigf(float v) { return 1.0f / (1.0f + expf(-v)); }

// ---------------- bias precompute ----------------
__global__ void bias_kernel(const float* __restrict__ ebih, const float* __restrict__ ebhh,
                            const float* __restrict__ dbih, const float* __restrict__ dbhh,
                            float* __restrict__ bsum, float* __restrict__ btot) {
  int i = blockIdx.x * 256 + threadIdx.x;
  if (i < 4 * EMB) bsum[i] = ebih[i] + ebhh[i];
  if (i < 4 * INP) btot[i] = dbih[i] + dbhh[i];
}

// ---------------- Wfold = (dec_Wih + dec_Whh) @ dec_Whr  (1828 x 480, pad cols zero) ----------------
__global__ __launch_bounds__(256) void fold_gemm(const float* __restrict__ dWih,
                                                 const float* __restrict__ dWhh,
                                                 const float* __restrict__ dWhr,
                                                 float* __restrict__ C) {
  const int bx = blockIdx.x, by = blockIdx.y;
  const int tid = threadIdx.x;
  const int tx = tid & 15, ty = tid >> 4;
  __shared__ float As[16][65];
  __shared__ float Bs[16][65];
  float acc[4][4] = {};
  for (int k0 = 0; k0 < EMB; k0 += 16) {
#pragma unroll
    for (int e = 0; e < 4; ++e) {
      int eid = tid * 4 + e;
      int m = eid >> 4, k = eid & 15;
      int row = by * 64 + m;
      float v = 0.0f;
      if (row < 4 * INP) {
        size_t a = (size_t)row * EMB + k0 + k;
        v = dWih[a] + dWhh[a];
      }
      As[k][m] = v;
    }
#pragma unroll
    for (int e = 0; e < 4; ++e) {
      int eid = tid * 4 + e;
      int k = eid >> 6, c = eid & 63;
      int col = bx * 64 + c;
      Bs[k][c] = (col < INP) ? dWhr[(size_t)(k0 + k) * INP + col] : 0.0f;
    }
    __syncthreads();
#pragma unroll
    for (int k = 0; k < 16; ++k) {
      float a0 = As[k][ty * 4 + 0], a1 = As[k][ty * 4 + 1], a2 = As[k][ty * 4 + 2], a3 = As[k][ty * 4 + 3];
      float b0 = Bs[k][tx * 4 + 0], b1 = Bs[k][tx * 4 + 1], b2 = Bs[k][tx * 4 + 2], b3 = Bs[k][tx * 4 + 3];
      acc[0][0] += a0 * b0; acc[0][1] += a0 * b1; acc[0][2] += a0 * b2; acc[0][3] += a0 * b3;
      acc[1][0] += a1 * b0; acc[1][1] += a1 * b1; acc[1][2] += a1 * b2; acc[1][3] += a1 * b3;
      acc[2][0] += a2 * b0; acc[2][1] += a2 * b1; acc[2][2] += a2 * b2; acc[2][3] += a2 * b3;
      acc[3][0] += a3 * b0; acc[3][1] += a3 * b1; acc[3][2] += a3 * b2; acc[3][3] += a3 * b3;
    }
    __syncthreads();
  }
#pragma unroll
  for (int i = 0; i < 4; ++i) {
    int row = by * 64 + ty * 4 + i;
    if (row >= 4 * INP) continue;
#pragma unroll
    for (int j = 0; j < 4; ++j) {
      int col = bx * 64 + tx * 4 + j;
      if (col < 480) C[(size_t)row * 480 + col] = acc[i][j];
    }
  }
}

// ---------------- persistent encoder ----------------
// 256 WGs x 1024 thr. WG w owns h-indices [w*8, w*8+8). Thread: j = tid&7, kc = tid>>3 (128 chunks of 16).
// Regs: Whh 4 gates x 4 float4 = 64 + Wih 4 floats x 4 = 16 -> ~116 VGPR total; fits 128 cap at 16 waves/CU.
// Sync: per-WG epoch STORE -> s_waitcnt vmcnt(0) (no threadfence / no L2 flush) -> wave0 read-only poll.
__global__ __launch_bounds__(1024, 1) void enc_kernel(
    const float* __restrict__ x, const float* __restrict__ Wih,
    const float* __restrict__ Whh, const float* __restrict__ bsum,
    float* __restrict__ hbuf, unsigned* __restrict__ ep) {
  const int tid = threadIdx.x;
  const int wg  = blockIdx.x;
  const int j   = tid & 7;
  const int kc  = tid >> 3;            // 0..127
  const int jbase = wg * 8;

  float4 whh4[4][4];
  float4 wih4[4];
#pragma unroll
  for (int g = 0; g < 4; ++g) {
    const size_t row = (size_t)(g * EMB + jbase + j);
    const float* wp = Whh + row * EMB + kc * 16;
#pragma unroll
    for (int q = 0; q < 4; ++q) whh4[g][q] = *(const float4*)(wp + 4 * q);
    const float* ip = Wih + row * INP;
    float tmp[4];
#pragma unroll
    for (int i = 0; i < 4; ++i) {
      const int c = kc * 4 + i;
      tmp[i] = (c < INP) ? ip[c] : 0.0f;
    }
    wih4[g] = make_float4(tmp[0], tmp[1], tmp[2], tmp[3]);
  }

  __shared__ float4 hl4[512];          // 8 KB: h_t (2048 floats)
  __shared__ float4 xl4[128];          // 2 KB: x_t (512 floats, pad 0)
  __shared__ float  partbuf[512];      // 16 waves x 8 j x 4 gates
  __shared__ float  b_s[32];
  __shared__ float  c_s[8];
  if (tid < 32) b_s[tid] = bsum[(tid >> 3) * EMB + jbase + (tid & 7)];
  if (tid < 8)  c_s[tid] = 0.0f;

  for (int t = 0; t < SEQ; ++t) {
    // ---- wave 0: wait for all 256 WGs to have posted epoch >= t (read-only poll) ----
    if (t > 0 && tid < 64) {
      const unsigned target = (unsigned)t;
      const unsigned* e4 = ep + tid * 4;
      for (;;) {
        const unsigned e0 = __hip_atomic_load(e4 + 0, __ATOMIC_RELAXED, __HIP_MEMORY_SCOPE_AGENT);
        const unsigned e1 = __hip_atomic_load(e4 + 1, __ATOMIC_RELAXED, __HIP_MEMORY_SCOPE_AGENT);
        const unsigned e2 = __hip_atomic_load(e4 + 2, __ATOMIC_RELAXED, __HIP_MEMORY_SCOPE_AGENT);
        const unsigned e3 = __hip_atomic_load(e4 + 3, __ATOMIC_RELAXED, __HIP_MEMORY_SCOPE_AGENT);
        unsigned mn = e0 < e1 ? e0 : e1;
        const unsigned m2 = e2 < e3 ? e2 : e3;
        mn = mn < m2 ? mn : m2;
        if (__all(mn >= target)) break;
        __builtin_amdgcn_s_sleep(2);
      }
    }
    __syncthreads();

    // ---- stage h_t and x_t into LDS ----
    {
      const u64t u = __hip_atomic_load((const u64t*)(hbuf + (size_t)(t & 1) * EMB) + tid,
                                       __ATOMIC_RELAXED, __HIP_MEMORY_SCOPE_AGENT);
      ((float2*)hl4)[tid] = __builtin_bit_cast(float2, u);
      if (tid < 512) {
        float xv = (tid < INP) ? x[(size_t)t * INP + tid] : 0.0f;
        ((float*)xl4)[tid] = xv;
      }
    }
    __syncthreads();

    // ---- MAC: 4 gates x (4 x-floats + 16 h-floats) ----
    float4 a0 = make_float4(0, 0, 0, 0), a1 = a0, a2 = a0, a3 = a0;
    {
      const float4 xv = xl4[kc];
      a0.x += wih4[0].x * xv.x; a0.y += wih4[0].y * xv.y; a0.z += wih4[0].z * xv.z; a0.w += wih4[0].w * xv.w;
      a1.x += wih4[1].x * xv.x; a1.y += wih4[1].y * xv.y; a1.z += wih4[1].z * xv.z; a1.w += wih4[1].w * xv.w;
      a2.x += wih4[2].x * xv.x; a2.y += wih4[2].y * xv.y; a2.z += wih4[2].z * xv.z; a2.w += wih4[2].w * xv.w;
      a3.x += wih4[3].x * xv.x; a3.y += wih4[3].y * xv.y; a3.z += wih4[3].z * xv.z; a3.w += wih4[3].w * xv.w;
    }
#pragma unroll
    for (int q = 0; q < 4; ++q) {
      const float4 hv = hl4[kc * 4 + q];
      a0.x += whh4[0][q].x * hv.x; a0.y += whh4[0][q].y * hv.y; a0.z += whh4[0][q].z * hv.z; a0.w += whh4[0][q].w * hv.w;
      a1.x += whh4[1][q].x * hv.x; a1.y += whh4[1][q].y * hv.y; a1.z += whh4[1][q].z * hv.z; a1.w += whh4[1][q].w * hv.w;
      a2.x += whh4[2][q].x * hv.x; a2.y += whh4[2][q].y * hv.y; a2.z += whh4[2][q].z * hv.z; a2.w += whh4[2][q].w * hv.w;
      a3.x += whh4[3][q].x * hv.x; a3.y += whh4[3][q].y * hv.y; a3.z += whh4[3][q].z * hv.z; a3.w += whh4[3][q].w * hv.w;
    }

    // ---- reduce 8 kc-chunks inside each wave (lane bits 3,4,5), partials to LDS ----
    float r0 = (a0.x + a0.y) + (a0.z + a0.w);
    float r1 = (a1.x + a1.y) + (a1.z + a1.w);
    float r2 = (a2.x + a2.y) + (a2.z + a2.w);
    float r3 = (a3.x + a3.y) + (a3.z + a3.w);
#pragma unroll
    for (int m = 8; m < 64; m <<= 1) {
      r0 += __shfl_xor(r0, m); r1 += __shfl_xor(r1, m);
      r2 += __shfl_xor(r2, m); r3 += __shfl_xor(r3, m);
    }
    if ((tid & 63) < 8) {
      float* pb = partbuf + (tid >> 6) * 32 + j * 4;
      pb[0] = r0; pb[1] = r1; pb[2] = r2; pb[3] = r3;
    }
    __syncthreads();

    // ---- activation + h_{t+1} store (tid<8, wave 0) ----
    if (tid < 8) {
      float s0 = 0.f, s1 = 0.f, s2 = 0.f, s3 = 0.f;
#pragma unroll
      for (int w = 0; w < 16; ++w) {
        const float* pb = partbuf + w * 32 + tid * 4;
        s0 += pb[0]; s1 += pb[1]; s2 += pb[2]; s3 += pb[3];
      }
      const float gi = s0 + b_s[tid], gf = s1 + b_s[8 + tid];
      const float gg = s2 + b_s[16 + tid], go = s3 + b_s[24 + tid];
      const float cN = sigf(gf) * c_s[tid] + sigf(gi) * tanhf(gg);
      c_s[tid] = cN;
      const float hN = sigf(go) * tanhf(cN);
      __hip_atomic_store(hbuf + (size_t)((t + 1) & 1) * EMB + jbase + tid, hN,
                         __ATOMIC_RELAXED, __HIP_MEMORY_SCOPE_AGENT);
    }
    // store-ack at coherence point, then post epoch (no L2 flush)
    asm volatile("s_waitcnt vmcnt(0)" ::: "memory");
    if (tid == 0)
      __hip_atomic_store(ep + wg, (unsigned)(t + 1), __ATOMIC_RELAXED, __HIP_MEMORY_SCOPE_AGENT);
  }
}

// ---------------- persistent decoder ----------------
// 16 WGs x 512 thr. WG w owns c-indices [w*32, w*32+32). Thread: j = tid&31, kc = tid>>5 (16 chunks of 30).
// Regs: Wfold 4 gates x 15 float2 = 120 -> ~150 VGPR, fits 256 cap at 8 waves/CU.
__global__ __launch_bounds__(512, 1) void dec_kernel(
    const float* __restrict__ dWih, const float* __restrict__ Wfold,
    const float* __restrict__ btot, const float* __restrict__ henc,
    float* __restrict__ hraw, float* __restrict__ out, unsigned* __restrict__ ep) {
  const int tid = threadIdx.x;
  const int wg  = blockIdx.x;
  const int j   = tid & 31;
  const int kc  = tid >> 5;          // 0..15
  const int idx = wg * 32 + j;
  const bool valid = (idx < INP);
  const int id0 = valid ? idx : 0;

  float2 wd2[4][15];
#pragma unroll
  for (int g = 0; g < 4; ++g) {
    const float* wp = Wfold + (size_t)(g * INP + id0) * 480 + kc * 30;
#pragma unroll
    for (int q = 0; q < 15; ++q)
      wd2[g][q] = valid ? *(const float2*)(wp + 2 * q) : make_float2(0.0f, 0.0f);
  }

  __shared__ float4 dl4[120];      // 480 floats: staged hraw
  __shared__ float  partbuf[1024]; // 8 waves x 32 j x 4 gates
  __shared__ float  b_s[128];
  __shared__ float  c_s[32];
  if (tid < 128) {
    const int ix = wg * 32 + (tid & 31);
    b_s[tid] = (ix < INP) ? btot[(tid >> 5) * INP + ix] : 0.0f;
  }
  if (tid < 32) c_s[tid] = 0.0f;

  for (int t = 0; t < SEQ; ++t) {
    if (t > 0 && tid < 64) {
      const unsigned target = (unsigned)t;
      const unsigned e = __hip_atomic_load(ep + (tid < 16 ? tid : 15),
                                           __ATOMIC_RELAXED, __HIP_MEMORY_SCOPE_AGENT);
      unsigned ev = e;
      while (!__all(ev >= target)) {
        __builtin_amdgcn_s_sleep(2);
        ev = __hip_atomic_load(ep + (tid < 16 ? tid : 15),
                               __ATOMIC_RELAXED, __HIP_MEMORY_SCOPE_AGENT);
      }
    }
    __syncthreads();
    if (t > 0 && tid < 240) {
      const u64t u = __hip_atomic_load((const u64t*)(hraw + (size_t)(t & 1) * 512) + tid,
                                       __ATOMIC_RELAXED, __HIP_MEMORY_SCOPE_AGENT);
      ((float2*)dl4)[tid] = __builtin_bit_cast(float2, u);
    }
    __syncthreads();

    float2 acc0 = make_float2(0, 0), acc1 = acc0, acc2 = acc0, acc3 = acc0;
    if (t == 0) {
      if (valid) {
#pragma unroll 4
        for (int q = 0; q < 32; ++q) {
          const float4 hv = *(const float4*)(henc + kc * 128 + 4 * q);
          const float4 w0 = *(const float4*)(dWih + (size_t)(0 * INP + idx) * EMB + kc * 128 + 4 * q);
          const float4 w1 = *(const float4*)(dWih + (size_t)(1 * INP + idx) * EMB + kc * 128 + 4 * q);
          const float4 w2 = *(const float4*)(dWih + (size_t)(2 * INP + idx) * EMB + kc * 128 + 4 * q);
          const float4 w3 = *(const float4*)(dWih + (size_t)(3 * INP + idx) * EMB + kc * 128 + 4 * q);
          acc0.x += w0.x * hv.x + w0.z * hv.z; acc0.y += w0.y * hv.y + w0.w * hv.w;
          acc1.x += w1.x * hv.x + w1.z * hv.z; acc1.y += w1.y * hv.y + w1.w * hv.w;
          acc2.x += w2.x * hv.x + w2.z * hv.z; acc2.y += w2.y * hv.y + w2.w * hv.w;
          acc3.x += w3.x * hv.x + w3.z * hv.z; acc3.y += w3.y * hv.y + w3.w * hv.w;
        }
      }
    } else {
      const float2* dl2 = (const float2*)dl4;
#pragma unroll
      for (int q = 0; q < 15; ++q) {
        const float2 hv = dl2[kc * 15 + q];
        acc0.x += wd2[0][q].x * hv.x; acc0.y += wd2[0][q].y * hv.y;
        acc1.x += wd2[1][q].x * hv.x; acc1.y += wd2[1][q].y * hv.y;
        acc2.x += wd2[2][q].x * hv.x; acc2.y += wd2[2][q].y * hv.y;
        acc3.x += wd2[3][q].x * hv.x; acc3.y += wd2[3][q].y * hv.y;
      }
    }
    float r0 = acc0.x + acc0.y, r1 = acc1.x + acc1.y, r2 = acc2.x + acc2.y, r3 = acc3.x + acc3.y;
    r0 += __shfl_xor(r0, 32); r1 += __shfl_xor(r1, 32);
    r2 += __shfl_xor(r2, 32); r3 += __shfl_xor(r3, 32);
    if ((tid & 63) < 32) {
      float* pb = partbuf + (tid >> 6) * 128 + (tid & 31) * 4;
      pb[0] = r0; pb[1] = r1; pb[2] = r2; pb[3] = r3;
    }
    __syncthreads();
    if (tid < 32) {
      float s0 = 0.f, s1 = 0.f, s2 = 0.f, s3 = 0.f;
#pragma unroll
      for (int w = 0; w < 8; ++w) {
        const float* pb = partbuf + w * 128 + tid * 4;
        s0 += pb[0]; s1 += pb[1]; s2 += pb[2]; s3 += pb[3];
      }
      const float gi = s0 + b_s[tid], gf = s1 + b_s[32 + tid];
      const float gg = s2 + b_s[64 + tid], go = s3 + b_s[96 + tid];
      const float cN = sigf(gf) * c_s[tid] + sigf(gi) * tanhf(gg);
      c_s[tid] = cN;
      const int ix = wg * 32 + tid;
      if (ix < INP) {
        out[(size_t)(SEQ - 1 - t) * INP + ix] = cN;
        const float hrN = sigf(go) * tanhf(cN);
        __hip_atomic_store(hraw + (size_t)((t + 1) & 1) * 512 + ix, hrN,
                           __ATOMIC_RELAXED, __HIP_MEMORY_SCOPE_AGENT);
      }
    }
    asm volatile("s_waitcnt vmcnt(0)" ::: "memory");
    if (tid == 0)
      __hip_atomic_store(ep + wg, (unsigned)(t + 1), __ATOMIC_RELAXED, __HIP_MEMORY_SCOPE_AGENT);
  }
}

// ---------------- row softmax in-place on d_out (4096 x 457) ----------------
__global__ __launch_bounds__(512) void softmax_kernel(float* __restrict__ out) {
  const int row = blockIdx.x;
  const int tid = threadIdx.x;
  __shared__ float red[512];
  float* rp = out + (size_t)row * INP;
  float v = (tid < INP) ? rp[tid] : -INFINITY;
  red[tid] = v;
  __syncthreads();
#pragma unroll
  for (int off = 256; off > 0; off >>= 1) {
    if (tid < off) red[tid] = fmaxf(red[tid], red[tid + off]);
    __syncthreads();
  }
  const float m = red[0];
  __syncthreads();
  const float e = (tid < INP) ? expf(v - m) : 0.0f;
  red[tid] = e;
  __syncthreads();
#pragma unroll
  for (int off = 256; off > 0; off >>= 1) {
    if (tid < off) red[tid] = red[tid] + red[tid + off];
    __syncthreads();
  }
  const float s = red[0];
  if (tid < INP) rp[tid] = e / s;
}

extern "C" void kernel_launch(void* const* d_in, const int* in_sizes, int n_in,
                              void* d_out, int out_size, void* d_ws, size_t ws_size,
                              hipStream_t stream) {
  const float* x    = (const float*)d_in[0];
  const float* eWih = (const float*)d_in[1];
  const float* eWhh = (const float*)d_in[2];
  const float* ebih = (const float*)d_in[3];
  const float* ebhh = (const float*)d_in[4];
  const float* dWih = (const float*)d_in[5];
  const float* dWhh = (const float*)d_in[6];
  const float* dbih = (const float*)d_in[7];
  const float* dbhh = (const float*)d_in[8];
  const float* dWhr = (const float*)d_in[9];
  float* out = (float*)d_out;
  char* ws = (char*)d_ws;

  // ws layout:
  // [0,1024):        enc epochs ep[256]
  // [1024,1152):     dec epochs ep[16]
  // [4096,20480):    hbuf 2x2048 f32 (double-buffered h; buf0 = h0 = 0; final h_enc lands in buf0)
  // [20480,24576):   hraw 2x512 f32 (zero-padded tail stays zero)
  // [24576,57344):   bsum
  // [57344,65536):   btot
  // [65536,+3.5MB):  Wfold 1828x480
  unsigned* ep_e = (unsigned*)(ws + 0);
  unsigned* ep_d = (unsigned*)(ws + 1024);
  float* hbuf  = (float*)(ws + 4096);
  float* hraw  = (float*)(ws + 4096 + 16384);
  float* bsum  = (float*)(ws + 24576);
  float* btot  = (float*)(ws + 24576 + 32768);
  float* Wfold = (float*)(ws + 65536);

  hipMemsetAsync(ws, 0, 24576, stream);  // epochs + hbuf + hraw
  bias_kernel<<<40, 256, 0, stream>>>(ebih, ebhh, dbih, dbhh, bsum, btot);
  fold_gemm<<<dim3(8, 29), 256, 0, stream>>>(dWih, dWhh, dWhr, Wfold);
  enc_kernel<<<NWG_E, 1024, 0, stream>>>(x, eWih, eWhh, bsum, hbuf, ep_e);
  dec_kernel<<<NWG_D, 512, 0, stream>>>(dWih, Wfold, btot, hbuf, hraw, out, ep_d);
  softmax_kernel<<<SEQ, 512, 0, stream>>>(out);
}

// Round 6
// 36223.871 us; speedup vs baseline: 1.8860x; 1.8860x over previous
//
#include <hip/hip_runtime.h>
#include <cmath>

#define SEQ 4096
#define INP 457
#define EMB 2048
#define NWG_E 256   // encoder: 1 WG (512 thr) per CU; 160 weight floats/thread pinned in VGPRs
#define NWG_D 16    // decoder: 16 WGs x 32 c-indices = 512 >= 457

typedef unsigned long long u64t;

__device__ __forceinline__ float sigf(float v) { return 1.0f / (1.0f + expf(-v)); }

// Opaque pin: value becomes output of an opaque asm -> compiler cannot rematerialize
// the original load; the value must stay live in a VGPR.
#define PIN(v) asm volatile("" : "+v"(v))

// ---------------- bias precompute ----------------
__global__ void bias_kernel(const float* __restrict__ ebih, const float* __restrict__ ebhh,
                            const float* __restrict__ dbih, const float* __restrict__ dbhh,
                            float* __restrict__ bsum, float* __restrict__ btot) {
  int i = blockIdx.x * 256 + threadIdx.x;
  if (i < 4 * EMB) bsum[i] = ebih[i] + ebhh[i];
  if (i < 4 * INP) btot[i] = dbih[i] + dbhh[i];
}

// ---------------- Wfold = (dec_Wih + dec_Whh) @ dec_Whr  (1828 x 480, pad cols zero) ----------------
__global__ __launch_bounds__(256) void fold_gemm(const float* __restrict__ dWih,
                                                 const float* __restrict__ dWhh,
                                                 const float* __restrict__ dWhr,
                                                 float* __restrict__ C) {
  const int bx = blockIdx.x, by = blockIdx.y;
  const int tid = threadIdx.x;
  const int tx = tid & 15, ty = tid >> 4;
  __shared__ float As[16][65];
  __shared__ float Bs[16][65];
  float acc[4][4] = {};
  for (int k0 = 0; k0 < EMB; k0 += 16) {
#pragma unroll
    for (int e = 0; e < 4; ++e) {
      int eid = tid * 4 + e;
      int m = eid >> 4, k = eid & 15;
      int row = by * 64 + m;
      float v = 0.0f;
      if (row < 4 * INP) {
        size_t a = (size_t)row * EMB + k0 + k;
        v = dWih[a] + dWhh[a];
      }
      As[k][m] = v;
    }
#pragma unroll
    for (int e = 0; e < 4; ++e) {
      int eid = tid * 4 + e;
      int k = eid >> 6, c = eid & 63;
      int col = bx * 64 + c;
      Bs[k][c] = (col < INP) ? dWhr[(size_t)(k0 + k) * INP + col] : 0.0f;
    }
    __syncthreads();
#pragma unroll
    for (int k = 0; k < 16; ++k) {
      float a0 = As[k][ty * 4 + 0], a1 = As[k][ty * 4 + 1], a2 = As[k][ty * 4 + 2], a3 = As[k][ty * 4 + 3];
      float b0 = Bs[k][tx * 4 + 0], b1 = Bs[k][tx * 4 + 1], b2 = Bs[k][tx * 4 + 2], b3 = Bs[k][tx * 4 + 3];
      acc[0][0] += a0 * b0; acc[0][1] += a0 * b1; acc[0][2] += a0 * b2; acc[0][3] += a0 * b3;
      acc[1][0] += a1 * b0; acc[1][1] += a1 * b1; acc[1][2] += a1 * b2; acc[1][3] += a1 * b3;
      acc[2][0] += a2 * b0; acc[2][1] += a2 * b1; acc[2][2] += a2 * b2; acc[2][3] += a2 * b3;
      acc[3][0] += a3 * b0; acc[3][1] += a3 * b1; acc[3][2] += a3 * b2; acc[3][3] += a3 * b3;
    }
    __syncthreads();
  }
#pragma unroll
  for (int i = 0; i < 4; ++i) {
    int row = by * 64 + ty * 4 + i;
    if (row >= 4 * INP) continue;
#pragma unroll
    for (int j = 0; j < 4; ++j) {
      int col = bx * 64 + tx * 4 + j;
      if (col < 480) C[(size_t)row * 480 + col] = acc[i][j];
    }
  }
}

// ---------------- persistent encoder ----------------
// 256 WGs x 512 thr, exactly 2 waves/EU (256-VGPR budget). WG w owns h-indices [w*8, w*8+8).
// Thread: j = tid&7, kc = tid>>3 (64 chunks of 32 k). Weights: Whh 4x32 + Wih 4x8 = 160 floats,
// PINNED in VGPRs via opaque asm (rematerialization impossible).
// h via agent atomics -> LDS, XOR-swizzled 16B granules: logical granule l stored at
// phys = l ^ ((l>>3)&7); read of slot kc*8+(q^sw) yields LOGICAL granule kc*8+q, so the
// matching weight granule is q (bug in r5 used q^sw - fixed).
// Barrier: per-WG epoch STORE + s_waitcnt vmcnt(0) ack + wave0 read-only poll (verified r4).
__global__ __launch_bounds__(512) __attribute__((amdgpu_waves_per_eu(2, 2))) void enc_kernel(
    const float* __restrict__ x, const float* __restrict__ Wih,
    const float* __restrict__ Whh, const float* __restrict__ bsum,
    float* __restrict__ hbuf, unsigned* __restrict__ ep) {
  const int tid = threadIdx.x;
  const int wg  = blockIdx.x;
  const int j   = tid & 7;
  const int kc  = tid >> 3;            // 0..63
  const int jbase = wg * 8;

  float wh[4][32];
  float wi[4][8];
#pragma unroll
  for (int g = 0; g < 4; ++g) {
    const size_t row = (size_t)(g * EMB + jbase + j);
    const float* wp = Whh + row * EMB + kc * 32;
#pragma unroll
    for (int q = 0; q < 8; ++q) {
      const float4 v = *(const float4*)(wp + 4 * q);
      wh[g][q * 4 + 0] = v.x; wh[g][q * 4 + 1] = v.y;
      wh[g][q * 4 + 2] = v.z; wh[g][q * 4 + 3] = v.w;
    }
    const float* ip = Wih + row * INP;
#pragma unroll
    for (int i = 0; i < 8; ++i) {
      const int c = kc * 8 + i;
      wi[g][i] = (c < INP) ? ip[c] : 0.0f;
    }
  }
  // pin all 160 weight floats in VGPRs
#pragma unroll
  for (int g = 0; g < 4; ++g) {
#pragma unroll
    for (int q = 0; q < 32; ++q) PIN(wh[g][q]);
#pragma unroll
    for (int q = 0; q < 8; ++q) PIN(wi[g][q]);
  }

  __shared__ float4 hl4[512];          // 8 KB: h_t, swizzled 16B granules
  __shared__ float4 xl4[128];          // 2 KB: x_t (512 floats, pad 0)
  __shared__ float  partbuf[256];      // 8 waves x 8 j x 4 gates
  __shared__ float  b_s[32];
  __shared__ float  c_s[8];
  if (tid < 32) b_s[tid] = bsum[(tid >> 3) * EMB + jbase + (tid & 7)];
  if (tid < 8)  c_s[tid] = 0.0f;
  const int sw = kc & 7;
  const int hphys = tid ^ ((tid >> 3) & 7);   // write-side granule swizzle

  for (int t = 0; t < SEQ; ++t) {
    // ---- wave 0: wait until all 256 WGs posted epoch >= t (read-only poll) ----
    if (t > 0 && tid < 64) {
      const unsigned target = (unsigned)t;
      const unsigned* e4 = ep + tid * 4;
      for (;;) {
        const unsigned e0 = __hip_atomic_load(e4 + 0, __ATOMIC_RELAXED, __HIP_MEMORY_SCOPE_AGENT);
        const unsigned e1 = __hip_atomic_load(e4 + 1, __ATOMIC_RELAXED, __HIP_MEMORY_SCOPE_AGENT);
        const unsigned e2 = __hip_atomic_load(e4 + 2, __ATOMIC_RELAXED, __HIP_MEMORY_SCOPE_AGENT);
        const unsigned e3 = __hip_atomic_load(e4 + 3, __ATOMIC_RELAXED, __HIP_MEMORY_SCOPE_AGENT);
        unsigned mn = e0 < e1 ? e0 : e1;
        const unsigned m2 = e2 < e3 ? e2 : e3;
        mn = mn < m2 ? mn : m2;
        if (__all(mn >= target)) break;
        __builtin_amdgcn_s_sleep(2);
      }
    }
    __syncthreads();

    // ---- stage h_t (4 floats/thread, agent atomics) + x_t into LDS ----
    {
      const u64t* hs = (const u64t*)(hbuf + (size_t)(t & 1) * EMB) + tid * 2;
      const u64t u0 = __hip_atomic_load(hs + 0, __ATOMIC_RELAXED, __HIP_MEMORY_SCOPE_AGENT);
      const u64t u1 = __hip_atomic_load(hs + 1, __ATOMIC_RELAXED, __HIP_MEMORY_SCOPE_AGENT);
      const float2 f0 = __builtin_bit_cast(float2, u0);
      const float2 f1 = __builtin_bit_cast(float2, u1);
      hl4[hphys] = make_float4(f0.x, f0.y, f1.x, f1.y);
      float xv = (tid < INP) ? x[(size_t)t * INP + tid] : 0.0f;
      ((float*)xl4)[tid] = xv;
    }
    __syncthreads();

    // ---- MAC: 4 gates x (8 x + 32 h) ----
    float4 a0 = make_float4(0, 0, 0, 0), a1 = a0, a2 = a0, a3 = a0;
#pragma unroll
    for (int q = 0; q < 2; ++q) {
      const float4 xv = xl4[kc * 2 + q];
      a0.x += wi[0][q * 4 + 0] * xv.x; a0.y += wi[0][q * 4 + 1] * xv.y; a0.z += wi[0][q * 4 + 2] * xv.z; a0.w += wi[0][q * 4 + 3] * xv.w;
      a1.x += wi[1][q * 4 + 0] * xv.x; a1.y += wi[1][q * 4 + 1] * xv.y; a1.z += wi[1][q * 4 + 2] * xv.z; a1.w += wi[1][q * 4 + 3] * xv.w;
      a2.x += wi[2][q * 4 + 0] * xv.x; a2.y += wi[2][q * 4 + 1] * xv.y; a2.z += wi[2][q * 4 + 2] * xv.z; a2.w += wi[2][q * 4 + 3] * xv.w;
      a3.x += wi[3][q * 4 + 0] * xv.x; a3.y += wi[3][q * 4 + 1] * xv.y; a3.z += wi[3][q * 4 + 2] * xv.z; a3.w += wi[3][q * 4 + 3] * xv.w;
    }
#pragma unroll
    for (int q = 0; q < 8; ++q) {
      const float4 hv = hl4[kc * 8 + (q ^ sw)];   // holds LOGICAL granule kc*8+q
      const int b = q * 4;                         // matching weight granule is q (r5 bug fixed)
      a0.x += wh[0][b + 0] * hv.x; a0.y += wh[0][b + 1] * hv.y; a0.z += wh[0][b + 2] * hv.z; a0.w += wh[0][b + 3] * hv.w;
      a1.x += wh[1][b + 0] * hv.x; a1.y += wh[1][b + 1] * hv.y; a1.z += wh[1][b + 2] * hv.z; a1.w += wh[1][b + 3] * hv.w;
      a2.x += wh[2][b + 0] * hv.x; a2.y += wh[2][b + 1] * hv.y; a2.z += wh[2][b + 2] * hv.z; a2.w += wh[2][b + 3] * hv.w;
      a3.x += wh[3][b + 0] * hv.x; a3.y += wh[3][b + 1] * hv.y; a3.z += wh[3][b + 2] * hv.z; a3.w += wh[3][b + 3] * hv.w;
    }

    // ---- reduce 8 kc-chunks inside each wave (lane bits 3,4,5), partials to LDS ----
    float r0 = (a0.x + a0.y) + (a0.z + a0.w);
    float r1 = (a1.x + a1.y) + (a1.z + a1.w);
    float r2 = (a2.x + a2.y) + (a2.z + a2.w);
    float r3 = (a3.x + a3.y) + (a3.z + a3.w);
#pragma unroll
    for (int m = 8; m < 64; m <<= 1) {
      r0 += __shfl_xor(r0, m); r1 += __shfl_xor(r1, m);
      r2 += __shfl_xor(r2, m); r3 += __shfl_xor(r3, m);
    }
    if ((tid & 63) < 8) {
      float* pb = partbuf + (tid >> 6) * 32 + j * 4;
      pb[0] = r0; pb[1] = r1; pb[2] = r2; pb[3] = r3;
    }
    __syncthreads();

    // ---- activation + h_{t+1} store (tid<8, wave 0) ----
    if (tid < 8) {
      float s0 = 0.f, s1 = 0.f, s2 = 0.f, s3 = 0.f;
#pragma unroll
      for (int w = 0; w < 8; ++w) {
        const float* pb = partbuf + w * 32 + tid * 4;
        s0 += pb[0]; s1 += pb[1]; s2 += pb[2]; s3 += pb[3];
      }
      const float gi = s0 + b_s[tid], gf = s1 + b_s[8 + tid];
      const float gg = s2 + b_s[16 + tid], go = s3 + b_s[24 + tid];
      const float cN = sigf(gf) * c_s[tid] + sigf(gi) * tanhf(gg);
      c_s[tid] = cN;
      const float hN = sigf(go) * tanhf(cN);
      __hip_atomic_store(hbuf + (size_t)((t + 1) & 1) * EMB + jbase + tid, hN,
                         __ATOMIC_RELAXED, __HIP_MEMORY_SCOPE_AGENT);
    }
    // store-ack at coherence point, then post epoch (no L2 flush)
    asm volatile("s_waitcnt vmcnt(0)" ::: "memory");
    if (tid == 0)
      __hip_atomic_store(ep + wg, (unsigned)(t + 1), __ATOMIC_RELAXED, __HIP_MEMORY_SCOPE_AGENT);
  }
}

// ---------------- persistent decoder ----------------
// 16 WGs x 512 thr. WG w owns c-indices [w*32, w*32+32). Thread: j = tid&31, kc = tid>>5.
// Wfold 4 gates x 30 = 120 floats, pinned.
__global__ __launch_bounds__(512) __attribute__((amdgpu_waves_per_eu(2, 2))) void dec_kernel(
    const float* __restrict__ dWih, const float* __restrict__ Wfold,
    const float* __restrict__ btot, const float* __restrict__ henc,
    float* __restrict__ hraw, float* __restrict__ out, unsigned* __restrict__ ep) {
  const int tid = threadIdx.x;
  const int wg  = blockIdx.x;
  const int j   = tid & 31;
  const int kc  = tid >> 5;          // 0..15
  const int idx = wg * 32 + j;
  const bool valid = (idx < INP);
  const int id0 = valid ? idx : 0;

  float wd[4][30];
#pragma unroll
  for (int g = 0; g < 4; ++g) {
    const float* wp = Wfold + (size_t)(g * INP + id0) * 480 + kc * 30;
#pragma unroll
    for (int q = 0; q < 15; ++q) {
      const float2 v = valid ? *(const float2*)(wp + 2 * q) : make_float2(0.0f, 0.0f);
      wd[g][q * 2 + 0] = v.x; wd[g][q * 2 + 1] = v.y;
    }
  }
#pragma unroll
  for (int g = 0; g < 4; ++g)
#pragma unroll
    for (int q = 0; q < 30; ++q) PIN(wd[g][q]);

  __shared__ float2 dl2[240];      // 480 floats: staged hraw
  __shared__ float  partbuf[1024]; // 8 waves x 32 j x 4 gates
  __shared__ float  b_s[128];
  __shared__ float  c_s[32];
  if (tid < 128) {
    const int ix = wg * 32 + (tid & 31);
    b_s[tid] = (ix < INP) ? btot[(tid >> 5) * INP + ix] : 0.0f;
  }
  if (tid < 32) c_s[tid] = 0.0f;

  for (int t = 0; t < SEQ; ++t) {
    if (t > 0 && tid < 64) {
      const unsigned target = (unsigned)t;
      unsigned ev = __hip_atomic_load(ep + (tid < NWG_D ? tid : NWG_D - 1),
                                      __ATOMIC_RELAXED, __HIP_MEMORY_SCOPE_AGENT);
      while (!__all(ev >= target)) {
        __builtin_amdgcn_s_sleep(2);
        ev = __hip_atomic_load(ep + (tid < NWG_D ? tid : NWG_D - 1),
                               __ATOMIC_RELAXED, __HIP_MEMORY_SCOPE_AGENT);
      }
    }
    __syncthreads();
    if (t > 0 && tid < 240) {
      const u64t u = __hip_atomic_load((const u64t*)(hraw + (size_t)(t & 1) * 512) + tid,
                                       __ATOMIC_RELAXED, __HIP_MEMORY_SCOPE_AGENT);
      dl2[tid] = __builtin_bit_cast(float2, u);
    }
    __syncthreads();

    float2 acc0 = make_float2(0, 0), acc1 = acc0, acc2 = acc0, acc3 = acc0;
    if (t == 0) {
      if (valid) {
#pragma unroll 4
        for (int q = 0; q < 32; ++q) {
          const float4 hv = *(const float4*)(henc + kc * 128 + 4 * q);
          const float4 w0 = *(const float4*)(dWih + (size_t)(0 * INP + idx) * EMB + kc * 128 + 4 * q);
          const float4 w1 = *(const float4*)(dWih + (size_t)(1 * INP + idx) * EMB + kc * 128 + 4 * q);
          const float4 w2 = *(const float4*)(dWih + (size_t)(2 * INP + idx) * EMB + kc * 128 + 4 * q);
          const float4 w3 = *(const float4*)(dWih + (size_t)(3 * INP + idx) * EMB + kc * 128 + 4 * q);
          acc0.x += w0.x * hv.x + w0.z * hv.z; acc0.y += w0.y * hv.y + w0.w * hv.w;
          acc1.x += w1.x * hv.x + w1.z * hv.z; acc1.y += w1.y * hv.y + w1.w * hv.w;
          acc2.x += w2.x * hv.x + w2.z * hv.z; acc2.y += w2.y * hv.y + w2.w * hv.w;
          acc3.x += w3.x * hv.x + w3.z * hv.z; acc3.y += w3.y * hv.y + w3.w * hv.w;
        }
      }
    } else {
#pragma unroll
      for (int q = 0; q < 15; ++q) {
        const float2 hv = dl2[kc * 15 + q];
        acc0.x += wd[0][q * 2] * hv.x; acc0.y += wd[0][q * 2 + 1] * hv.y;
        acc1.x += wd[1][q * 2] * hv.x; acc1.y += wd[1][q * 2 + 1] * hv.y;
        acc2.x += wd[2][q * 2] * hv.x; acc2.y += wd[2][q * 2 + 1] * hv.y;
        acc3.x += wd[3][q * 2] * hv.x; acc3.y += wd[3][q * 2 + 1] * hv.y;
      }
    }
    float r0 = acc0.x + acc0.y, r1 = acc1.x + acc1.y, r2 = acc2.x + acc2.y, r3 = acc3.x + acc3.y;
    r0 += __shfl_xor(r0, 32); r1 += __shfl_xor(r1, 32);
    r2 += __shfl_xor(r2, 32); r3 += __shfl_xor(r3, 32);
    if ((tid & 63) < 32) {
      float* pb = partbuf + (tid >> 6) * 128 + (tid & 31) * 4;
      pb[0] = r0; pb[1] = r1; pb[2] = r2; pb[3] = r3;
    }
    __syncthreads();
    if (tid < 32) {
      float s0 = 0.f, s1 = 0.f, s2 = 0.f, s3 = 0.f;
#pragma unroll
      for (int w = 0; w < 8; ++w) {
        const float* pb = partbuf + w * 128 + tid * 4;
        s0 += pb[0]; s1 += pb[1]; s2 += pb[2]; s3 += pb[3];
      }
      const float gi = s0 + b_s[tid], gf = s1 + b_s[32 + tid];
      const float gg = s2 + b_s[64 + tid], go = s3 + b_s[96 + tid];
      const float cN = sigf(gf) * c_s[tid] + sigf(gi) * tanhf(gg);
      c_s[tid] = cN;
      const int ix = wg * 32 + tid;
      if (ix < INP) {
        out[(size_t)(SEQ - 1 - t) * INP + ix] = cN;
        const float hrN = sigf(go) * tanhf(cN);
        __hip_atomic_store(hraw + (size_t)((t + 1) & 1) * 512 + ix, hrN,
                           __ATOMIC_RELAXED, __HIP_MEMORY_SCOPE_AGENT);
      }
    }
    asm volatile("s_waitcnt vmcnt(0)" ::: "memory");
    if (tid == 0)
      __hip_atomic_store(ep + wg, (unsigned)(t + 1), __ATOMIC_RELAXED, __HIP_MEMORY_SCOPE_AGENT);
  }
}

// ---------------- row softmax in-place on d_out (4096 x 457) ----------------
__global__ __launch_bounds__(512) void softmax_kernel(float* __restrict__ out) {
  const int row = blockIdx.x;
  const int tid = threadIdx.x;
  __shared__ float red[512];
  float* rp = out + (size_t)row * INP;
  float v = (tid < INP) ? rp[tid] : -INFINITY;
  red[tid] = v;
  __syncthreads();
#pragma unroll
  for (int off = 256; off > 0; off >>= 1) {
    if (tid < off) red[tid] = fmaxf(red[tid], red[tid + off]);
    __syncthreads();
  }
  const float m = red[0];
  __syncthreads();
  const float e = (tid < INP) ? expf(v - m) : 0.0f;
  red[tid] = e;
  __syncthreads();
#pragma unroll
  for (int off = 256; off > 0; off >>= 1) {
    if (tid < off) red[tid] = red[tid] + red[tid + off];
    __syncthreads();
  }
  const float s = red[0];
  if (tid < INP) rp[tid] = e / s;
}

extern "C" void kernel_launch(void* const* d_in, const int* in_sizes, int n_in,
                              void* d_out, int out_size, void* d_ws, size_t ws_size,
                              hipStream_t stream) {
  const float* x    = (const float*)d_in[0];
  const float* eWih = (const float*)d_in[1];
  const float* eWhh = (const float*)d_in[2];
  const float* ebih = (const float*)d_in[3];
  const float* ebhh = (const float*)d_in[4];
  const float* dWih = (const float*)d_in[5];
  const float* dWhh = (const float*)d_in[6];
  const float* dbih = (const float*)d_in[7];
  const float* dbhh = (const float*)d_in[8];
  const float* dWhr = (const float*)d_in[9];
  float* out = (float*)d_out;
  char* ws = (char*)d_ws;

  // ws layout:
  // [0,1024):        enc epochs ep[256]
  // [1024,1152):     dec epochs ep[16]
  // [4096,20480):    hbuf 2x2048 f32 (double-buffered h; buf0 = h0 = 0; final h_enc in buf0)
  // [20480,24576):   hraw 2x512 f32 (zero-padded tail stays zero)
  // [24576,57344):   bsum
  // [57344,65536):   btot
  // [65536,+3.5MB):  Wfold 1828x480
  unsigned* ep_e = (unsigned*)(ws + 0);
  unsigned* ep_d = (unsigned*)(ws + 1024);
  float* hbuf  = (float*)(ws + 4096);
  float* hraw  = (float*)(ws + 4096 + 16384);
  float* bsum  = (float*)(ws + 24576);
  float* btot  = (float*)(ws + 24576 + 32768);
  float* Wfold = (float*)(ws + 65536);

  hipMemsetAsync(ws, 0, 24576, stream);  // epochs + hbuf + hraw
  bias_kernel<<<40, 256, 0, stream>>>(ebih, ebhh, dbih, dbhh, bsum, btot);
  fold_gemm<<<dim3(8, 29), 256, 0, stream>>>(dWih, dWhh, dWhr, Wfold);
  enc_kernel<<<NWG_E, 512, 0, stream>>>(x, eWih, eWhh, bsum, hbuf, ep_e);
  dec_kernel<<<NWG_D, 512, 0, stream>>>(dWih, Wfold, btot, hbuf, hraw, out, ep_d);
  softmax_kernel<<<SEQ, 512, 0, stream>>>(out);
}